// Round 3
// baseline (232.252 us; speedup 1.0000x reference)
//
#include <hip/hip_runtime.h>

// Two gaussians per thread. Block = 256 threads -> 512 gaussians/block.
// Quats: 2 coalesced float4 loads/lane. Scales: direct per-thread 12 B loads
// (stride-12 across lanes is contiguous per wave -> coalesced; no LDS stage,
// no first barrier). Outputs: staged in LDS, drained as 1152 coalesced 16 B
// regular stores (L2 absorbs the write stream at fill-rate; nt-stores
// measurably hurt in round 2 since the 576 MB poison fill flushes L3 anyway).
// LDS = 18 KB/block -> 8 blocks/CU = 32 waves/CU.

__device__ __forceinline__ void cov_from_quat(
    const float4 q, const float s0, const float s1, const float s2,
    float* __restrict__ so)
{
    const float invn = rsqrtf(q.x * q.x + q.y * q.y + q.z * q.z + q.w * q.w);
    const float w = q.x * invn, x = q.y * invn, y = q.z * invn, z = q.w * invn;

    const float r00 = 1.f - 2.f * (y * y + z * z);
    const float r01 = 2.f * (x * y - w * z);
    const float r02 = 2.f * (x * z + w * y);
    const float r10 = 2.f * (x * y + w * z);
    const float r11 = 1.f - 2.f * (x * x + z * z);
    const float r12 = 2.f * (y * z - w * x);
    const float r20 = 2.f * (x * z - w * y);
    const float r21 = 2.f * (y * z + w * x);
    const float r22 = 1.f - 2.f * (x * x + y * y);

    // M[i][j] = R[i][j] * s[j]
    const float m00 = r00 * s0, m01 = r01 * s1, m02 = r02 * s2;
    const float m10 = r10 * s0, m11 = r11 * s1, m12 = r12 * s2;
    const float m20 = r20 * s0, m21 = r21 * s1, m22 = r22 * s2;

    // cov = M * M^T (symmetric)
    const float c00 = m00 * m00 + m01 * m01 + m02 * m02;
    const float c01 = m00 * m10 + m01 * m11 + m02 * m12;
    const float c02 = m00 * m20 + m01 * m21 + m02 * m22;
    const float c11 = m10 * m10 + m11 * m11 + m12 * m12;
    const float c12 = m10 * m20 + m11 * m21 + m12 * m22;
    const float c22 = m20 * m20 + m21 * m21 + m22 * m22;

    // stride-9 LDS write: gcd(9,32)=1 -> 2 lanes/bank over wave64, free.
    so[0] = c00; so[1] = c01; so[2] = c02;
    so[3] = c01; so[4] = c11; so[5] = c12;
    so[6] = c02; so[7] = c12; so[8] = c22;
}

__global__ __launch_bounds__(256) void cov_main_kernel(
    const float4* __restrict__ rot4,
    const float* __restrict__ scale,
    float4* __restrict__ out4)
{
    __shared__ __align__(16) float s_out[4608];     // 512 * 9 = 18 KB
    const int t = threadIdx.x;
    const long long b = blockIdx.x;

    // All global reads issued up front: 32 B quat + 24 B scale per lane.
    const float4 q0 = rot4[b * 512 + t];
    const float4 q1 = rot4[b * 512 + 256 + t];

    const float* sp0 = scale + (b * 512 + t) * 3;          // 12 B, contiguous/wave
    const float* sp1 = scale + (b * 512 + 256 + t) * 3;
    const float a0 = sp0[0], a1 = sp0[1], a2 = sp0[2];
    const float b0 = sp1[0], b1 = sp1[1], b2 = sp1[2];

    cov_from_quat(q0, a0, a1, a2, &s_out[t * 9]);
    cov_from_quat(q1, b0, b1, b2, &s_out[(t + 256) * 9]);
    __syncthreads();

    // Drain 1152 float4 per block, fully coalesced 16 B stores.
    const float4* sv = (const float4*)s_out;
    float4* ob = out4 + b * 1152;
    ob[t]        = sv[t];
    ob[t + 256]  = sv[t + 256];
    ob[t + 512]  = sv[t + 512];
    ob[t + 768]  = sv[t + 768];
    if (t < 128)
        ob[t + 1024] = sv[t + 1024];
}

// Tail path: scalar, bounds-checked (handles N % 512 = 256 for N=4,000,000).
__global__ void cov_tail_kernel(
    const float* __restrict__ rot,
    const float* __restrict__ scale,
    float* __restrict__ out,
    int start, int n)
{
    int i = start + blockIdx.x * blockDim.x + threadIdx.x;
    if (i >= n) return;
    const float qw = rot[i * 4 + 0], qx = rot[i * 4 + 1];
    const float qy = rot[i * 4 + 2], qz = rot[i * 4 + 3];
    const float s0 = scale[i * 3 + 0], s1 = scale[i * 3 + 1], s2 = scale[i * 3 + 2];
    const float invn = rsqrtf(qw * qw + qx * qx + qy * qy + qz * qz);
    const float w = qw * invn, x = qx * invn, y = qy * invn, z = qz * invn;
    const float r00 = 1.f - 2.f * (y * y + z * z);
    const float r01 = 2.f * (x * y - w * z);
    const float r02 = 2.f * (x * z + w * y);
    const float r10 = 2.f * (x * y + w * z);
    const float r11 = 1.f - 2.f * (x * x + z * z);
    const float r12 = 2.f * (y * z - w * x);
    const float r20 = 2.f * (x * z - w * y);
    const float r21 = 2.f * (y * z + w * x);
    const float r22 = 1.f - 2.f * (x * x + y * y);
    const float m00 = r00 * s0, m01 = r01 * s1, m02 = r02 * s2;
    const float m10 = r10 * s0, m11 = r11 * s1, m12 = r12 * s2;
    const float m20 = r20 * s0, m21 = r21 * s1, m22 = r22 * s2;
    float* o = out + (size_t)i * 9;
    o[0] = m00 * m00 + m01 * m01 + m02 * m02;
    o[1] = m00 * m10 + m01 * m11 + m02 * m12;
    o[2] = m00 * m20 + m01 * m21 + m02 * m22;
    o[3] = o[1];
    o[4] = m10 * m10 + m11 * m11 + m12 * m12;
    o[5] = m10 * m20 + m11 * m21 + m12 * m22;
    o[6] = o[2];
    o[7] = o[5];
    o[8] = m20 * m20 + m21 * m21 + m22 * m22;
}

extern "C" void kernel_launch(void* const* d_in, const int* in_sizes, int n_in,
                              void* d_out, int out_size, void* d_ws, size_t ws_size,
                              hipStream_t stream) {
    const float* rot   = (const float*)d_in[0];   // (N,4) fp32
    const float* scale = (const float*)d_in[1];   // (N,3) fp32
    float* out = (float*)d_out;                   // (N,3,3) fp32

    const int N = in_sizes[0] / 4;
    const int nfull = N / 512;          // full blocks of 512 gaussians
    const int rem_start = nfull * 512;
    const int rem = N - rem_start;

    if (nfull > 0) {
        cov_main_kernel<<<nfull, 256, 0, stream>>>(
            (const float4*)rot, scale, (float4*)out);
    }
    if (rem > 0) {
        cov_tail_kernel<<<(rem + 255) / 256, 256, 0, stream>>>(
            rot, scale, out, rem_start, N);
    }
}

// Round 4
// 230.504 us; speedup vs baseline: 1.0076x; 1.0076x over previous
//
#include <hip/hip_runtime.h>

// Persistent, double-buffered streaming pipeline. 1 gaussian/thread-iteration,
// 256 threads/block, grid = 2048 blocks (8/CU), grid-stride over 256-gaussian
// tiles. Per iteration: compute tile t into LDS buf p, ISSUE tile t+1's global
// loads (quat float4 + scale 12B direct, both coalesced), barrier, drain buf p
// as 576 coalesced float4 stores while t+1's loads are in flight. Read and
// write streams stay simultaneously outstanding — fill-kernel-style streaming.
// One barrier/tile (round 0 had two). LDS = 2 x 9 KB -> 8 blocks/CU.
// nt-stores hurt (round 2): poison fill flushes L3 anyway, and L2
// write-absorption is what makes the regular store stream fast.

__device__ __forceinline__ void cov_from_quat(
    const float4 q, const float s0, const float s1, const float s2,
    float* __restrict__ so)
{
    const float invn = rsqrtf(q.x * q.x + q.y * q.y + q.z * q.z + q.w * q.w);
    const float w = q.x * invn, x = q.y * invn, y = q.z * invn, z = q.w * invn;

    const float r00 = 1.f - 2.f * (y * y + z * z);
    const float r01 = 2.f * (x * y - w * z);
    const float r02 = 2.f * (x * z + w * y);
    const float r10 = 2.f * (x * y + w * z);
    const float r11 = 1.f - 2.f * (x * x + z * z);
    const float r12 = 2.f * (y * z - w * x);
    const float r20 = 2.f * (x * z - w * y);
    const float r21 = 2.f * (y * z + w * x);
    const float r22 = 1.f - 2.f * (x * x + y * y);

    const float m00 = r00 * s0, m01 = r01 * s1, m02 = r02 * s2;
    const float m10 = r10 * s0, m11 = r11 * s1, m12 = r12 * s2;
    const float m20 = r20 * s0, m21 = r21 * s1, m22 = r22 * s2;

    const float c00 = m00 * m00 + m01 * m01 + m02 * m02;
    const float c01 = m00 * m10 + m01 * m11 + m02 * m12;
    const float c02 = m00 * m20 + m01 * m21 + m02 * m22;
    const float c11 = m10 * m10 + m11 * m11 + m12 * m12;
    const float c12 = m10 * m20 + m11 * m21 + m12 * m22;
    const float c22 = m20 * m20 + m21 * m21 + m22 * m22;

    // stride-9 LDS write: gcd(9,32)=1 -> 2 lanes/bank over wave64, free.
    so[0] = c00; so[1] = c01; so[2] = c02;
    so[3] = c01; so[4] = c11; so[5] = c12;
    so[6] = c02; so[7] = c12; so[8] = c22;
}

__global__ __launch_bounds__(256) void cov_main_kernel(
    const float4* __restrict__ rot4,
    const float* __restrict__ scale,
    float4* __restrict__ out4,
    int ntiles)
{
    __shared__ __align__(16) float s_out[2][2304];   // 2 x 256*9 floats = 18.4 KB
    const int t = threadIdx.x;
    const int stride = gridDim.x;

    int tile = blockIdx.x;
    if (tile >= ntiles) return;

    // Prologue: loads for the first tile.
    float4 q = rot4[(long long)tile * 256 + t];
    const float* sp = scale + ((long long)tile * 256 + t) * 3;
    float s0 = sp[0], s1 = sp[1], s2 = sp[2];

    int p = 0;
    for (;;) {
        // Compute current tile into LDS buffer p.
        cov_from_quat(q, s0, s1, s2, &s_out[p][t * 9]);

        // Issue next tile's global loads BEFORE the barrier/drain so the read
        // stream overlaps the store stream.
        const int next = tile + stride;
        const bool more = next < ntiles;
        if (more) {
            q = rot4[(long long)next * 256 + t];
            const float* sp2 = scale + ((long long)next * 256 + t) * 3;
            s0 = sp2[0]; s1 = sp2[1]; s2 = sp2[2];
        }

        __syncthreads();   // buf p fully written; also fences prior drain reads

        // Drain buffer p: 576 coalesced float4 stores per tile.
        const float4* sv = (const float4*)s_out[p];
        float4* ob = out4 + (long long)tile * 576;
        ob[t]       = sv[t];
        ob[t + 256] = sv[t + 256];
        if (t < 64) ob[t + 512] = sv[t + 512];

        if (!more) break;
        tile = next;
        p ^= 1;
    }
}

// Tail path: scalar, bounds-checked. Not launched for N % 256 == 0 (N=4M).
__global__ void cov_tail_kernel(
    const float* __restrict__ rot,
    const float* __restrict__ scale,
    float* __restrict__ out,
    int start, int n)
{
    int i = start + blockIdx.x * blockDim.x + threadIdx.x;
    if (i >= n) return;
    const float qw = rot[i * 4 + 0], qx = rot[i * 4 + 1];
    const float qy = rot[i * 4 + 2], qz = rot[i * 4 + 3];
    const float s0 = scale[i * 3 + 0], s1 = scale[i * 3 + 1], s2 = scale[i * 3 + 2];
    const float invn = rsqrtf(qw * qw + qx * qx + qy * qy + qz * qz);
    const float w = qw * invn, x = qx * invn, y = qy * invn, z = qz * invn;
    const float r00 = 1.f - 2.f * (y * y + z * z);
    const float r01 = 2.f * (x * y - w * z);
    const float r02 = 2.f * (x * z + w * y);
    const float r10 = 2.f * (x * y + w * z);
    const float r11 = 1.f - 2.f * (x * x + z * z);
    const float r12 = 2.f * (y * z - w * x);
    const float r20 = 2.f * (x * z - w * y);
    const float r21 = 2.f * (y * z + w * x);
    const float r22 = 1.f - 2.f * (x * x + y * y);
    const float m00 = r00 * s0, m01 = r01 * s1, m02 = r02 * s2;
    const float m10 = r10 * s0, m11 = r11 * s1, m12 = r12 * s2;
    const float m20 = r20 * s0, m21 = r21 * s1, m22 = r22 * s2;
    float* o = out + (size_t)i * 9;
    o[0] = m00 * m00 + m01 * m01 + m02 * m02;
    o[1] = m00 * m10 + m01 * m11 + m02 * m12;
    o[2] = m00 * m20 + m01 * m21 + m02 * m22;
    o[3] = o[1];
    o[4] = m10 * m10 + m11 * m11 + m12 * m12;
    o[5] = m10 * m20 + m11 * m21 + m12 * m22;
    o[6] = o[2];
    o[7] = o[5];
    o[8] = m20 * m20 + m21 * m21 + m22 * m22;
}

extern "C" void kernel_launch(void* const* d_in, const int* in_sizes, int n_in,
                              void* d_out, int out_size, void* d_ws, size_t ws_size,
                              hipStream_t stream) {
    const float* rot   = (const float*)d_in[0];   // (N,4) fp32
    const float* scale = (const float*)d_in[1];   // (N,3) fp32
    float* out = (float*)d_out;                   // (N,3,3) fp32

    const int N = in_sizes[0] / 4;
    const int ntiles = N / 256;                    // full 256-gaussian tiles
    const int rem_start = ntiles * 256;
    const int rem = N - rem_start;

    if (ntiles > 0) {
        const int grid = ntiles < 2048 ? ntiles : 2048;   // 8 blocks/CU
        cov_main_kernel<<<grid, 256, 0, stream>>>(
            (const float4*)rot, scale, (float4*)out, ntiles);
    }
    if (rem > 0) {
        cov_tail_kernel<<<(rem + 255) / 256, 256, 0, stream>>>(
            rot, scale, out, rem_start, N);
    }
}

// Round 5
// 229.426 us; speedup vs baseline: 1.0123x; 1.0047x over previous
//
#include <hip/hip_runtime.h>

// Round-0 structure with the scale LDS stage removed (the one isolated change).
// One gaussian/thread, 256 threads/block, grid = N/256 (no tail for N=4M).
// Quat: coalesced float4 load. Scale: direct 12 B/lane load (stride-12 across
// a wave is a contiguous 768 B span -> coalesced dwordx3; LDS staging added a
// barrier + LDS round-trip for zero coalescing benefit). Output: staged in LDS
// (9 KB), drained as 576 coalesced float4 regular stores (nt-stores hurt in
// round 2 — the harness poison flushes L3 anyway and L2 absorbs the stream).
// Single barrier per block.

__global__ __launch_bounds__(256) void cov_main_kernel(
    const float4* __restrict__ rot4,
    const float* __restrict__ scale,
    float4* __restrict__ out4)
{
    __shared__ __align__(16) float s_out[2304];    // 256 * 9 = 9 KB
    const int t = threadIdx.x;
    const long long b = blockIdx.x;

    // All global reads up front: 16 B quat + 12 B scale per lane, coalesced.
    const float4 q = rot4[b * 256 + t];
    const float* sp = scale + (b * 256 + t) * 3;
    const float s0 = sp[0], s1 = sp[1], s2 = sp[2];

    const float invn = rsqrtf(q.x * q.x + q.y * q.y + q.z * q.z + q.w * q.w);
    const float w = q.x * invn, x = q.y * invn, y = q.z * invn, z = q.w * invn;

    const float r00 = 1.f - 2.f * (y * y + z * z);
    const float r01 = 2.f * (x * y - w * z);
    const float r02 = 2.f * (x * z + w * y);
    const float r10 = 2.f * (x * y + w * z);
    const float r11 = 1.f - 2.f * (x * x + z * z);
    const float r12 = 2.f * (y * z - w * x);
    const float r20 = 2.f * (x * z - w * y);
    const float r21 = 2.f * (y * z + w * x);
    const float r22 = 1.f - 2.f * (x * x + y * y);

    // M[i][j] = R[i][j] * s[j]
    const float m00 = r00 * s0, m01 = r01 * s1, m02 = r02 * s2;
    const float m10 = r10 * s0, m11 = r11 * s1, m12 = r12 * s2;
    const float m20 = r20 * s0, m21 = r21 * s1, m22 = r22 * s2;

    // cov = M * M^T (symmetric)
    const float c00 = m00 * m00 + m01 * m01 + m02 * m02;
    const float c01 = m00 * m10 + m01 * m11 + m02 * m12;
    const float c02 = m00 * m20 + m01 * m21 + m02 * m22;
    const float c11 = m10 * m10 + m11 * m11 + m12 * m12;
    const float c12 = m10 * m20 + m11 * m21 + m12 * m22;
    const float c22 = m20 * m20 + m21 * m21 + m22 * m22;

    // stride-9 LDS write: gcd(9,32)=1 -> 2 lanes/bank over wave64, free.
    float* so = &s_out[t * 9];
    so[0] = c00; so[1] = c01; so[2] = c02;
    so[3] = c01; so[4] = c11; so[5] = c12;
    so[6] = c02; so[7] = c12; so[8] = c22;
    __syncthreads();

    // Drain 576 float4 per block, fully coalesced 16 B stores.
    const float4* sv = (const float4*)s_out;
    float4* ob = out4 + b * 576;
    ob[t]       = sv[t];
    ob[t + 256] = sv[t + 256];
    if (t < 64) ob[t + 512] = sv[t + 512];
}

// Tail path (not launched for N % 256 == 0): scalar, bounds-checked.
__global__ void cov_tail_kernel(
    const float* __restrict__ rot,
    const float* __restrict__ scale,
    float* __restrict__ out,
    int start, int n)
{
    int i = start + blockIdx.x * blockDim.x + threadIdx.x;
    if (i >= n) return;
    const float qw = rot[i * 4 + 0], qx = rot[i * 4 + 1];
    const float qy = rot[i * 4 + 2], qz = rot[i * 4 + 3];
    const float s0 = scale[i * 3 + 0], s1 = scale[i * 3 + 1], s2 = scale[i * 3 + 2];
    const float invn = rsqrtf(qw * qw + qx * qx + qy * qy + qz * qz);
    const float w = qw * invn, x = qx * invn, y = qy * invn, z = qz * invn;
    const float r00 = 1.f - 2.f * (y * y + z * z);
    const float r01 = 2.f * (x * y - w * z);
    const float r02 = 2.f * (x * z + w * y);
    const float r10 = 2.f * (x * y + w * z);
    const float r11 = 1.f - 2.f * (x * x + z * z);
    const float r12 = 2.f * (y * z - w * x);
    const float r20 = 2.f * (x * z - w * y);
    const float r21 = 2.f * (y * z + w * x);
    const float r22 = 1.f - 2.f * (x * x + y * y);
    const float m00 = r00 * s0, m01 = r01 * s1, m02 = r02 * s2;
    const float m10 = r10 * s0, m11 = r11 * s1, m12 = r12 * s2;
    const float m20 = r20 * s0, m21 = r21 * s1, m22 = r22 * s2;
    float* o = out + (size_t)i * 9;
    o[0] = m00 * m00 + m01 * m01 + m02 * m02;
    o[1] = m00 * m10 + m01 * m11 + m02 * m12;
    o[2] = m00 * m20 + m01 * m21 + m02 * m22;
    o[3] = o[1];
    o[4] = m10 * m10 + m11 * m11 + m12 * m12;
    o[5] = m10 * m20 + m11 * m21 + m12 * m22;
    o[6] = o[2];
    o[7] = o[5];
    o[8] = m20 * m20 + m21 * m21 + m22 * m22;
}

extern "C" void kernel_launch(void* const* d_in, const int* in_sizes, int n_in,
                              void* d_out, int out_size, void* d_ws, size_t ws_size,
                              hipStream_t stream) {
    const float* rot   = (const float*)d_in[0];   // (N,4) fp32
    const float* scale = (const float*)d_in[1];   // (N,3) fp32
    float* out = (float*)d_out;                   // (N,3,3) fp32

    const int N = in_sizes[0] / 4;
    const int nfull = N / 256;          // full blocks of 256 gaussians
    const int rem_start = nfull * 256;
    const int rem = N - rem_start;

    if (nfull > 0) {
        cov_main_kernel<<<nfull, 256, 0, stream>>>(
            (const float4*)rot, scale, (float4*)out);
    }
    if (rem > 0) {
        cov_tail_kernel<<<(rem + 255) / 256, 256, 0, stream>>>(
            rot, scale, out, rem_start, N);
    }
}

// Round 6
// 226.706 us; speedup vs baseline: 1.0245x; 1.0120x over previous
//
#include <hip/hip_runtime.h>

// One thread per gaussian. Block = 256 threads. Best-measured configuration
// (225.7 us): quats via coalesced float4, scales staged through LDS via 192
// coalesced float4 loads, outputs staged in LDS and drained as 576 coalesced
// float4 stores. Rounds 2-5 falsified every alternative schedule (2 g/thr,
// nt-stores, direct scale loads, persistent double-buffered pipeline): all
// within measurement noise or worse. The kernel segment (~53 us, 256 MB,
// ~4.8 TB/s 3-stream mix) is schedule-invariant -> memory-system-bound.

__global__ __launch_bounds__(256) void cov_main_kernel(
    const float4* __restrict__ rot4,
    const float4* __restrict__ scale4,
    float4* __restrict__ out4)
{
    __shared__ float s_scale[768];                 // 256 * 3
    __shared__ __align__(16) float s_out[2304];    // 256 * 9
    const int t = threadIdx.x;
    const long long b = blockIdx.x;

    // Stage this block's scales: 768 floats = 192 float4, coalesced.
    if (t < 192) {
        ((float4*)s_scale)[t] = scale4[b * 192 + t];
    }
    // Quaternion load: 16B/lane, perfectly coalesced.
    float4 q = rot4[b * 256 + t];
    __syncthreads();

    // stride-3 LDS read: gcd(3,32)=1 -> 2 lanes/bank over wave64, free.
    const float s0 = s_scale[t * 3 + 0];
    const float s1 = s_scale[t * 3 + 1];
    const float s2 = s_scale[t * 3 + 2];

    const float invn = rsqrtf(q.x * q.x + q.y * q.y + q.z * q.z + q.w * q.w);
    const float w = q.x * invn, x = q.y * invn, y = q.z * invn, z = q.w * invn;

    const float r00 = 1.f - 2.f * (y * y + z * z);
    const float r01 = 2.f * (x * y - w * z);
    const float r02 = 2.f * (x * z + w * y);
    const float r10 = 2.f * (x * y + w * z);
    const float r11 = 1.f - 2.f * (x * x + z * z);
    const float r12 = 2.f * (y * z - w * x);
    const float r20 = 2.f * (x * z - w * y);
    const float r21 = 2.f * (y * z + w * x);
    const float r22 = 1.f - 2.f * (x * x + y * y);

    // M[i][j] = R[i][j] * s[j]
    const float m00 = r00 * s0, m01 = r01 * s1, m02 = r02 * s2;
    const float m10 = r10 * s0, m11 = r11 * s1, m12 = r12 * s2;
    const float m20 = r20 * s0, m21 = r21 * s1, m22 = r22 * s2;

    // cov = M * M^T (symmetric)
    const float c00 = m00 * m00 + m01 * m01 + m02 * m02;
    const float c01 = m00 * m10 + m01 * m11 + m02 * m12;
    const float c02 = m00 * m20 + m01 * m21 + m02 * m22;
    const float c11 = m10 * m10 + m11 * m11 + m12 * m12;
    const float c12 = m10 * m20 + m11 * m21 + m12 * m22;
    const float c22 = m20 * m20 + m21 * m21 + m22 * m22;

    // stride-9 LDS write: gcd(9,32)=1 -> 2-way aliasing over wave64, free.
    float* so = &s_out[t * 9];
    so[0] = c00; so[1] = c01; so[2] = c02;
    so[3] = c01; so[4] = c11; so[5] = c12;
    so[6] = c02; so[7] = c12; so[8] = c22;
    __syncthreads();

    // Drain 576 float4 per block, fully coalesced 16B stores.
    const float4* sv = (const float4*)s_out;
    float4* ob = out4 + b * 576;
    ob[t]       = sv[t];
    ob[t + 256] = sv[t + 256];
    if (t < 64) ob[t + 512] = sv[t + 512];
}

// Tail path (not expected to launch for N=4,000,000): scalar, bounds-checked.
__global__ void cov_tail_kernel(
    const float* __restrict__ rot,
    const float* __restrict__ scale,
    float* __restrict__ out,
    int start, int n)
{
    int i = start + blockIdx.x * blockDim.x + threadIdx.x;
    if (i >= n) return;
    const float qw = rot[i * 4 + 0], qx = rot[i * 4 + 1];
    const float qy = rot[i * 4 + 2], qz = rot[i * 4 + 3];
    const float s0 = scale[i * 3 + 0], s1 = scale[i * 3 + 1], s2 = scale[i * 3 + 2];
    const float invn = rsqrtf(qw * qw + qx * qx + qy * qy + qz * qz);
    const float w = qw * invn, x = qx * invn, y = qy * invn, z = qz * invn;
    const float r00 = 1.f - 2.f * (y * y + z * z);
    const float r01 = 2.f * (x * y - w * z);
    const float r02 = 2.f * (x * z + w * y);
    const float r10 = 2.f * (x * y + w * z);
    const float r11 = 1.f - 2.f * (x * x + z * z);
    const float r12 = 2.f * (y * z - w * x);
    const float r20 = 2.f * (x * z - w * y);
    const float r21 = 2.f * (y * z + w * x);
    const float r22 = 1.f - 2.f * (x * x + y * y);
    const float m00 = r00 * s0, m01 = r01 * s1, m02 = r02 * s2;
    const float m10 = r10 * s0, m11 = r11 * s1, m12 = r12 * s2;
    const float m20 = r20 * s0, m21 = r21 * s1, m22 = r22 * s2;
    float* o = out + (size_t)i * 9;
    o[0] = m00 * m00 + m01 * m01 + m02 * m02;
    o[1] = m00 * m10 + m01 * m11 + m02 * m12;
    o[2] = m00 * m20 + m01 * m21 + m02 * m22;
    o[3] = o[1];
    o[4] = m10 * m10 + m11 * m11 + m12 * m12;
    o[5] = m10 * m20 + m11 * m21 + m12 * m22;
    o[6] = o[2];
    o[7] = o[5];
    o[8] = m20 * m20 + m21 * m21 + m22 * m22;
}

extern "C" void kernel_launch(void* const* d_in, const int* in_sizes, int n_in,
                              void* d_out, int out_size, void* d_ws, size_t ws_size,
                              hipStream_t stream) {
    const float* rot   = (const float*)d_in[0];   // (N,4) fp32
    const float* scale = (const float*)d_in[1];   // (N,3) fp32
    float* out = (float*)d_out;                   // (N,3,3) fp32

    const int N = in_sizes[0] / 4;
    const int nfull = N / 256;          // full blocks of 256 gaussians
    const int rem_start = nfull * 256;
    const int rem = N - rem_start;

    if (nfull > 0) {
        cov_main_kernel<<<nfull, 256, 0, stream>>>(
            (const float4*)rot, (const float4*)scale, (float4*)out);
    }
    if (rem > 0) {
        cov_tail_kernel<<<(rem + 255) / 256, 256, 0, stream>>>(
            rot, scale, out, rem_start, N);
    }
}